// Round 2
// baseline (226.817 us; speedup 1.0000x reference)
//
#include <hip/hip_runtime.h>
#include <math.h>

// ---------------- types / helpers ----------------
typedef float f32x4 __attribute__((ext_vector_type(4)));
typedef __bf16 bf16x8 __attribute__((ext_vector_type(8)));
typedef unsigned short ushort_t;

#define MFMA16(a, b, c) __builtin_amdgcn_mfma_f32_16x16x32_bf16((a), (b), (c), 0, 0, 0)

static __device__ __forceinline__ ushort_t f2bf(float f) {
  union { float f; unsigned u; } v; v.f = f;
  unsigned u = v.u;
  return (ushort_t)((u + 0x7FFFu + ((u >> 16) & 1u)) >> 16);  // RNE
}
static __device__ __forceinline__ float bf2f(ushort_t h) {
  union { unsigned u; float f; } v; v.u = ((unsigned)h) << 16;
  return v.f;
}
// async global->LDS, 16B per lane; lds pointer must be wave-uniform (dest = base + lane*16)
static __device__ __forceinline__ void gl_lds16(const void* g, void* lds_uniform) {
  __builtin_amdgcn_global_load_lds(
      (const __attribute__((address_space(1))) unsigned int*)g,
      (__attribute__((address_space(3))) unsigned int*)lds_uniform, 16, 0, 0);
}

// ---------------- fused prep: x/w casts + RoPE table (1 launch) ----------
__global__ void prep(const float* __restrict__ x,
                     const float* __restrict__ wq, const float* __restrict__ wk,
                     const float* __restrict__ wv, const float* __restrict__ wo,
                     ushort_t* __restrict__ Xb, ushort_t* __restrict__ Wqb,
                     ushort_t* __restrict__ Wkb, ushort_t* __restrict__ Wvb,
                     ushort_t* __restrict__ Wob, float2* __restrict__ cs) {
  const int bid = blockIdx.x;
  if (bid < 12288) {
    const float* src;
    ushort_t* dst;
    int i;
    if (bid < 8192) {
      src = x; dst = Xb;
      i = bid * 256 + threadIdx.x;
    } else {
      const int wi = (bid - 8192) >> 10;
      src = (wi == 0) ? wq : (wi == 1) ? wk : (wi == 2) ? wv : wo;
      dst = (wi == 0) ? Wqb : (wi == 1) ? Wkb : (wi == 2) ? Wvb : Wob;
      i = ((bid - 8192) & 1023) * 256 + threadIdx.x;
    }
    f32x4 v = ((const f32x4*)src)[i];
    ushort4 o;
    o.x = f2bf(v.x); o.y = f2bf(v.y); o.z = f2bf(v.z); o.w = f2bf(v.w);
    ((ushort4*)dst)[i] = o;
  } else {
    int idx = (bid - 12288) * 256 + threadIdx.x;  // 4096*32 entries
    int pos = idx >> 5, i = idx & 31;
    double inv = exp2(-(double)i * 0.41524101186092029);  // log2(10000)/32
    double th = (double)pos * inv;
    double s, c;
    sincos(th, &s, &c);
    cs[idx] = make_float2((float)c, (float)s);
  }
}

// ---------------- m201-geometry 8-phase NT GEMM ----------------
// BM=BN=256, BK=64. 512 threads = 8 waves (2M x 4N), per-wave 128x64 output.
// C[m][n] = sum_k A[m][k]*W[n][k]. A: MxK bf16 rm, W: NxK bf16 rm.
// LDS 128 KiB: buf b at b*65536: A tile 32K, B tile 32K. XOR-swizzled chunk
// layout (slot = chunk ^ (row&7)) via pre-swizzled global source (0-conflict,
// verified in prior rounds).
//
// 4 phases per K-tile j (16 MFMA = one C-quadrant each). Staging runs TWO
// tiles ahead into the SAME-parity buffer; each 64-row quarter (one 8KB
// gl_lds16 across 512 thr) is issued only AFTER the barrier closing the phase
// that finished consuming that region:
//   P1: ds A m0-3 (8) + B n0-1 (4)      | stage: -          | MFMA m0-3 x n0-1
//   P2: ds B n2-3 (4)                   | stage QA0,QA2(j+2)| MFMA m0-3 x n2-3
//   P3: ds A m4-7 (8)                   | stage QB0,QB1(j+2)| MFMA m4-7 x n0-1
//   P4: -                               | stage QA1,QA3,QB2,QB3(j+2); vmcnt(8)
//                                                           | MFMA m4-7 x n2-3
// Region safety: P1 consumes A rows {0-63,128-191} (QA0,QA2); P2 consumes all
// of B; P3 consumes A rows {64-127,192-255}. vmcnt(8) retires tile j+1's 8
// loads (issued during j-1) and leaves tile j+2's 8 in flight across the
// boundary -- never drains to 0 mid-loop.
template <int OUTBF>
__global__ __launch_bounds__(512, 2) void gemm8(
    const ushort_t* __restrict__ A,
    const ushort_t* __restrict__ W0, const ushort_t* __restrict__ W1, const ushort_t* __restrict__ W2,
    void* __restrict__ C0, void* __restrict__ C1, void* __restrict__ C2,
    int K, int N) {
  __shared__ __align__(16) char smem[131072];
  const int z = blockIdx.z;
  const ushort_t* W = (z == 0) ? W0 : (z == 1 ? W1 : W2);
  void* Cv = (z == 0) ? C0 : (z == 1 ? C1 : C2);

  const int t = threadIdx.x;
  const int lane = t & 63;
  const int l15 = lane & 15, quad = lane >> 4;
  const int wave = t >> 6;
  const int wm = wave >> 2, wn = wave & 3;  // 2M x 4N, per-wave 128x64
  const int bm = blockIdx.x, bn = blockIdx.y;

  // staging: thread t -> row t>>3 (64 rows/quarter), LDS chunk t&7,
  // global chunk (t&7)^(row&7); quarter stride 64 rows keeps row&7 invariant.
  const int r0 = t >> 3;
  const int gc = (t & 7) ^ (r0 & 7);
  const ushort_t* AgB = A + (size_t)(bm * 256 + r0) * K + gc * 8;
  const ushort_t* WgB = W + (size_t)(bn * 256 + r0) * K + gc * 8;
  const size_t q64K = (size_t)64 * K;
  char* ldsw = smem + wave * 1024;  // wave-uniform dest (+ lane*16 by HW)

  // fragment read offsets (bytes within buffer). slot = (ks*4+quad)^(l15&7);
  // ks1 = ks0 ^ 4 slots -> byte ^64.
  const int sl0 = (quad ^ (l15 & 7)) * 16;
  const int aoff = (wm * 128 + l15) * 128 + sl0;          // + m*2048
  const int boff = 32768 + (wn * 64 + l15) * 128 + sl0;   // + n*2048

  const int KT = K >> 6;

  const f32x4 zero4 = {0.f, 0.f, 0.f, 0.f};
  f32x4 acc[8][4];
#pragma unroll
  for (int i = 0; i < 8; ++i)
#pragma unroll
    for (int j = 0; j < 4; ++j) acc[i][j] = zero4;

  auto stA = [&](int buf, int q, int kt) {
    gl_lds16(AgB + (size_t)q * q64K + (size_t)kt * 64, ldsw + buf * 65536 + q * 8192);
  };
  auto stB = [&](int buf, int q, int kt) {
    gl_lds16(WgB + (size_t)q * q64K + (size_t)kt * 64, ldsw + buf * 65536 + 32768 + q * 8192);
  };

  // prologue: tile0 -> buf0 (8), tile1 -> buf1 (8); retire tile0, keep tile1 in flight.
#pragma unroll
  for (int q = 0; q < 4; ++q) stA(0, q, 0);
#pragma unroll
  for (int q = 0; q < 4; ++q) stB(0, q, 0);
#pragma unroll
  for (int q = 0; q < 4; ++q) stA(1, q, 1);
#pragma unroll
  for (int q = 0; q < 4; ++q) stB(1, q, 1);
  asm volatile("s_waitcnt vmcnt(8)" ::: "memory");
  __builtin_amdgcn_s_barrier();

  bf16x8 af[4][2], b01[2][2], b23[2][2];

  for (int j = 0; j < KT; ++j) {
    const int cb = j & 1;
    const char* bufb = smem + cb * 65536;
    const bool pf = (j + 2 < KT);
    const int k2 = j + 2;

    // ---- P1: ds A m0-3 + B n0-1 ----
#pragma unroll
    for (int m = 0; m < 4; ++m) {
      const int o = aoff + m * 2048;
      af[m][0] = *(const bf16x8*)(bufb + o);
      af[m][1] = *(const bf16x8*)(bufb + (o ^ 64));
    }
#pragma unroll
    for (int n = 0; n < 2; ++n) {
      const int o = boff + n * 2048;
      b01[n][0] = *(const bf16x8*)(bufb + o);
      b01[n][1] = *(const bf16x8*)(bufb + (o ^ 64));
    }
    __builtin_amdgcn_s_barrier();
    asm volatile("s_waitcnt lgkmcnt(0)" ::: "memory");
    __builtin_amdgcn_sched_barrier(0);
    __builtin_amdgcn_s_setprio(1);
#pragma unroll
    for (int m = 0; m < 4; ++m)
#pragma unroll
      for (int n = 0; n < 2; ++n) {
        acc[m][n] = MFMA16(af[m][0], b01[n][0], acc[m][n]);
        acc[m][n] = MFMA16(af[m][1], b01[n][1], acc[m][n]);
      }
    __builtin_amdgcn_s_setprio(0);
    __builtin_amdgcn_sched_barrier(0);
    __builtin_amdgcn_s_barrier();

    // ---- P2: ds B n2-3; stage QA0,QA2(j+2) (A rows 0-63,128-191 freed by P1) ----
#pragma unroll
    for (int n = 0; n < 2; ++n) {
      const int o = boff + (n + 2) * 2048;
      b23[n][0] = *(const bf16x8*)(bufb + o);
      b23[n][1] = *(const bf16x8*)(bufb + (o ^ 64));
    }
    if (pf) { stA(cb, 0, k2); stA(cb, 2, k2); }
    __builtin_amdgcn_s_barrier();
    asm volatile("s_waitcnt lgkmcnt(0)" ::: "memory");
    __builtin_amdgcn_sched_barrier(0);
    __builtin_amdgcn_s_setprio(1);
#pragma unroll
    for (int m = 0; m < 4; ++m)
#pragma unroll
      for (int n = 0; n < 2; ++n) {
        acc[m][n + 2] = MFMA16(af[m][0], b23[n][0], acc[m][n + 2]);
        acc[m][n + 2] = MFMA16(af[m][1], b23[n][1], acc[m][n + 2]);
      }
    __builtin_amdgcn_s_setprio(0);
    __builtin_amdgcn_sched_barrier(0);
    __builtin_amdgcn_s_barrier();

    // ---- P3: ds A m4-7; stage QB0,QB1(j+2) (all B freed by P2) ----
#pragma unroll
    for (int m = 0; m < 4; ++m) {
      const int o = aoff + (m + 4) * 2048;
      af[m][0] = *(const bf16x8*)(bufb + o);
      af[m][1] = *(const bf16x8*)(bufb + (o ^ 64));
    }
    if (pf) { stB(cb, 0, k2); stB(cb, 1, k2); }
    __builtin_amdgcn_s_barrier();
    asm volatile("s_waitcnt lgkmcnt(0)" ::: "memory");
    __builtin_amdgcn_sched_barrier(0);
    __builtin_amdgcn_s_setprio(1);
#pragma unroll
    for (int m = 0; m < 4; ++m)
#pragma unroll
      for (int n = 0; n < 2; ++n) {
        acc[m + 4][n] = MFMA16(af[m][0], b01[n][0], acc[m + 4][n]);
        acc[m + 4][n] = MFMA16(af[m][1], b01[n][1], acc[m + 4][n]);
      }
    __builtin_amdgcn_s_setprio(0);
    __builtin_amdgcn_sched_barrier(0);
    __builtin_amdgcn_s_barrier();

    // ---- P4: stage QA1,QA3,QB2,QB3(j+2) (A rows 64-127,192-255 freed by P3);
    //          counted vmcnt keeps tile j+2 in flight across the boundary ----
    if (pf) {
      stA(cb, 1, k2); stA(cb, 3, k2);
      stB(cb, 2, k2); stB(cb, 3, k2);
      asm volatile("s_waitcnt vmcnt(8)" ::: "memory");
    } else if (j + 1 < KT) {
      asm volatile("s_waitcnt vmcnt(0)" ::: "memory");
    }
    __builtin_amdgcn_s_barrier();
    __builtin_amdgcn_s_setprio(1);
#pragma unroll
    for (int m = 0; m < 4; ++m)
#pragma unroll
      for (int n = 0; n < 2; ++n) {
        acc[m + 4][n + 2] = MFMA16(af[m][0], b23[n][0], acc[m + 4][n + 2]);
        acc[m + 4][n + 2] = MFMA16(af[m][1], b23[n][1], acc[m + 4][n + 2]);
      }
    __builtin_amdgcn_s_setprio(0);
    __builtin_amdgcn_sched_barrier(0);
    __builtin_amdgcn_s_barrier();
  }

  // ---- epilogue: C/D mapping col=l15, row=quad*4+r (verified) ----
  const int rbase = bm * 256 + wm * 128 + quad * 4;
  const int cbase = bn * 256 + wn * 64 + l15;
#pragma unroll
  for (int m = 0; m < 8; ++m)
#pragma unroll
    for (int n = 0; n < 4; ++n)
#pragma unroll
      for (int r = 0; r < 4; ++r) {
        size_t idx = (size_t)(rbase + m * 16 + r) * N + (cbase + n * 16);
        if (OUTBF)
          ((ushort_t*)Cv)[idx] = f2bf(acc[m][n][r]);
        else
          ((float*)Cv)[idx] = acc[m][n][r];
      }
}

// ---------------- fused windowed attention (unchanged) ----------------
static __device__ __forceinline__ void rope8(const ushort_t* __restrict__ g,
                                             ushort_t* __restrict__ lds,
                                             const float2* __restrict__ cs4, float scale) {
  uint4 raw = *(const uint4*)g;
  unsigned rw[4] = {raw.x, raw.y, raw.z, raw.w};
  ushort_t o[8];
#pragma unroll
  for (int m = 0; m < 4; ++m) {
    float x1 = bf2f((ushort_t)(rw[m] & 0xffffu));
    float x2 = bf2f((ushort_t)(rw[m] >> 16));
    float2 sc = cs4[m];
    o[2 * m]     = f2bf((x1 * sc.x - x2 * sc.y) * scale);
    o[2 * m + 1] = f2bf((x1 * sc.y + x2 * sc.x) * scale);
  }
  uint4 w;
  w.x = (unsigned)o[0] | ((unsigned)o[1] << 16);
  w.y = (unsigned)o[2] | ((unsigned)o[3] << 16);
  w.z = (unsigned)o[4] | ((unsigned)o[5] << 16);
  w.w = (unsigned)o[6] | ((unsigned)o[7] << 16);
  *(uint4*)lds = w;  // ds_write_b128
}

__global__ __launch_bounds__(256, 2) void attn(
    const ushort_t* __restrict__ Qb, const ushort_t* __restrict__ Kb,
    const ushort_t* __restrict__ Vb, ushort_t* __restrict__ Yb,
    const float2* __restrict__ cs) {
  __shared__ __align__(16) ushort_t smem[27648];
  ushort_t* Qs = smem;
  ushort_t* Ks = smem + 9216;
  ushort_t* Vt = smem;
  ushort_t* Pc = smem + 16896;

  const int t = threadIdx.x;
  const int lane = t & 63, wave = t >> 6;
  const int l15 = lane & 15, quad = lane >> 4;
  const int win = blockIdx.x >> 1, slice = blockIdx.x & 1;
  const int h = blockIdx.y, b = blockIdx.z;
  const int kBase = win * 256, qBase = kBase + slice * 128;
  const size_t gbase = ((size_t)b * 4096) * 1024 + h * 64;

  const int sr = t >> 3;
  const int c0 = (t & 7) * 8;

#pragma unroll
  for (int p = 0; p < 4; ++p) {
    int r = p * 32 + sr;
    rope8(Qb + gbase + (size_t)(qBase + r) * 1024 + c0, Qs + r * 72 + c0,
          cs + (qBase + r) * 32 + (c0 >> 1), 0.125f);
  }
#pragma unroll
  for (int p = 0; p < 8; ++p) {
    int r = p * 32 + sr;
    rope8(Kb + gbase + (size_t)(kBase + r) * 1024 + c0, Ks + r * 72 + c0,
          cs + (kBase + r) * 32 + (c0 >> 1), 1.0f);
  }
  __syncthreads();

  const int qw = wave * 32;
  const f32x4 zero4 = {0.f, 0.f, 0.f, 0.f};
  f32x4 S[2][16];
#pragma unroll
  for (int i = 0; i < 2; ++i)
#pragma unroll
    for (int j = 0; j < 16; ++j) S[i][j] = zero4;
#pragma unroll
  for (int ks = 0; ks < 2; ++ks) {
    bf16x8 a0 = *(const bf16x8*)&Qs[(qw + l15) * 72 + ks * 32 + quad * 8];
    bf16x8 a1 = *(const bf16x8*)&Qs[(qw + 16 + l15) * 72 + ks * 32 + quad * 8];
#pragma unroll
    for (int j = 0; j < 16; ++j) {
      bf16x8 bk = *(const bf16x8*)&Ks[(j * 16 + l15) * 72 + ks * 32 + quad * 8];
      S[0][j] = MFMA16(a0, bk, S[0][j]);
      S[1][j] = MFMA16(a1, bk, S[1][j]);
    }
  }

  float linv[2][4];
#pragma unroll
  for (int i = 0; i < 2; ++i)
#pragma unroll
    for (int r = 0; r < 4; ++r) {
      float mx = S[i][0][r];
#pragma unroll
      for (int j = 1; j < 16; ++j) mx = fmaxf(mx, S[i][j][r]);
      mx = fmaxf(mx, __shfl_xor(mx, 1));
      mx = fmaxf(mx, __shfl_xor(mx, 2));
      mx = fmaxf(mx, __shfl_xor(mx, 4));
      mx = fmaxf(mx, __shfl_xor(mx, 8));
      float sum = 0.f;
#pragma unroll
      for (int j = 0; j < 16; ++j) {
        float e = __expf(S[i][j][r] - mx);
        S[i][j][r] = e;
        sum += e;
      }
      sum += __shfl_xor(sum, 1);
      sum += __shfl_xor(sum, 2);
      sum += __shfl_xor(sum, 4);
      sum += __shfl_xor(sum, 8);
      linv[i][r] = 1.0f / sum;
    }
  __syncthreads();

#pragma unroll
  for (int p = 0; p < 8; ++p) {
    int k = p * 32 + sr;
    uint4 raw = *(const uint4*)(Vb + gbase + (size_t)(kBase + k) * 1024 + c0);
    ushort_t vv[8];
    vv[0] = raw.x & 0xffffu; vv[1] = raw.x >> 16;
    vv[2] = raw.y & 0xffffu; vv[3] = raw.y >> 16;
    vv[4] = raw.z & 0xffffu; vv[5] = raw.z >> 16;
    vv[6] = raw.w & 0xffffu; vv[7] = raw.w >> 16;
#pragma unroll
    for (int e = 0; e < 8; ++e) {
      int ee = (e + (t & 7)) & 7;
      Vt[(c0 + ee) * 264 + k] = vv[ee];
    }
  }

  auto writeP = [&](int kc) {
#pragma unroll
    for (int i = 0; i < 2; ++i)
#pragma unroll
      for (int jj = 0; jj < 4; ++jj) {
        int j = kc * 4 + jj;
#pragma unroll
        for (int r = 0; r < 4; ++r)
          Pc[(qw + i * 16 + quad * 4 + r) * 72 + jj * 16 + l15] = f2bf(S[i][j][r]);
      }
  };

  writeP(0);
  __syncthreads();

  f32x4 O[2][4];
#pragma unroll
  for (int i = 0; i < 2; ++i)
#pragma unroll
    for (int jd = 0; jd < 4; ++jd) O[i][jd] = zero4;

  for (int kc = 0; kc < 4; ++kc) {
#pragma unroll
    for (int ks = 0; ks < 2; ++ks) {
      bf16x8 a0 = *(const bf16x8*)&Pc[(qw + l15) * 72 + ks * 32 + quad * 8];
      bf16x8 a1 = *(const bf16x8*)&Pc[(qw + 16 + l15) * 72 + ks * 32 + quad * 8];
#pragma unroll
      for (int jd = 0; jd < 4; ++jd) {
        bf16x8 bv = *(const bf16x8*)&Vt[(jd * 16 + l15) * 264 + kc * 64 + ks * 32 + quad * 8];
        O[0][jd] = MFMA16(a0, bv, O[0][jd]);
        O[1][jd] = MFMA16(a1, bv, O[1][jd]);
      }
    }
    if (kc < 3) {
      __syncthreads();
      writeP(kc + 1);
      __syncthreads();
    }
  }

#pragma unroll
  for (int i = 0; i < 2; ++i)
#pragma unroll
    for (int jd = 0; jd < 4; ++jd)
#pragma unroll
      for (int r = 0; r < 4; ++r) {
        int row = qBase + qw + i * 16 + quad * 4 + r;
        int col = jd * 16 + l15;
        Yb[gbase + (size_t)row * 1024 + col] = f2bf(O[i][jd][r] * linv[i][r]);
      }
}

// ---------------- launch ----------------
extern "C" void kernel_launch(void* const* d_in, const int* in_sizes, int n_in,
                              void* d_out, int out_size, void* d_ws, size_t ws_size,
                              hipStream_t stream) {
  (void)in_sizes; (void)n_in; (void)out_size; (void)ws_size;
  const float* x  = (const float*)d_in[0];
  const float* wq = (const float*)d_in[1];
  const float* wk = (const float*)d_in[2];
  const float* wv = (const float*)d_in[3];
  const float* wo = (const float*)d_in[4];

  char* ws = (char*)d_ws;
  // workspace layout (bytes): Xb 16M | Wq..Wo 4x2M | Qb 16M | Kb 16M | Vb 16M | Yb 16M | cs 1M
  ushort_t* Xb  = (ushort_t*)(ws);
  ushort_t* Wqb = (ushort_t*)(ws + 16777216);
  ushort_t* Wkb = Wqb + 1048576;
  ushort_t* Wvb = Wkb + 1048576;
  ushort_t* Wob = Wvb + 1048576;
  ushort_t* Qb  = (ushort_t*)(ws + 25165824);
  ushort_t* Kb  = Qb + 8388608;
  ushort_t* Vb  = Kb + 8388608;
  ushort_t* Yb  = Vb + 8388608;
  float2*   cs  = (float2*)(ws + 92274688);

  prep<<<dim3(12800), dim3(256), 0, stream>>>(x, wq, wk, wv, wo,
                                              Xb, Wqb, Wkb, Wvb, Wob, cs);

  // QKV: M=8192, N=1024 -> 32x4x3 = 384 blocks (256^2 tiles)
  gemm8<1><<<dim3(32, 4, 3), dim3(512), 0, stream>>>(
      Xb, Wqb, Wkb, Wvb, (void*)Qb, (void*)Kb, (void*)Vb, 1024, 1024);

  attn<<<dim3(32, 16, 2), dim3(256), 0, stream>>>(Qb, Kb, Vb, Yb, cs);

  // proj: 32x4x1 = 128 blocks
  gemm8<0><<<dim3(32, 4, 1), dim3(512), 0, stream>>>(
      Yb, Wob, Wob, Wob, d_out, d_out, d_out, 1024, 1024);
}

// Round 3
// 205.634 us; speedup vs baseline: 1.1030x; 1.1030x over previous
//
#include <hip/hip_runtime.h>
#include <math.h>

// ---------------- types / helpers ----------------
typedef float f32x4 __attribute__((ext_vector_type(4)));
typedef __bf16 bf16x8 __attribute__((ext_vector_type(8)));
typedef unsigned short ushort_t;

#define MFMA16(a, b, c) __builtin_amdgcn_mfma_f32_16x16x32_bf16((a), (b), (c), 0, 0, 0)

static __device__ __forceinline__ ushort_t f2bf(float f) {
  union { float f; unsigned u; } v; v.f = f;
  unsigned u = v.u;
  return (ushort_t)((u + 0x7FFFu + ((u >> 16) & 1u)) >> 16);  // RNE
}
static __device__ __forceinline__ float bf2f(ushort_t h) {
  union { unsigned u; float f; } v; v.u = ((unsigned)h) << 16;
  return v.f;
}
// async global->LDS, 16B per lane; lds pointer must be wave-uniform (dest = base + lane*16)
static __device__ __forceinline__ void gl_lds16(const void* g, void* lds_uniform) {
  __builtin_amdgcn_global_load_lds(
      (const __attribute__((address_space(1))) unsigned int*)g,
      (__attribute__((address_space(3))) unsigned int*)lds_uniform, 16, 0, 0);
}

// ---------------- fused prep: x/w casts + RoPE table (1 launch) ----------
__global__ void prep(const float* __restrict__ x,
                     const float* __restrict__ wq, const float* __restrict__ wk,
                     const float* __restrict__ wv, const float* __restrict__ wo,
                     ushort_t* __restrict__ Xb, ushort_t* __restrict__ Wqb,
                     ushort_t* __restrict__ Wkb, ushort_t* __restrict__ Wvb,
                     ushort_t* __restrict__ Wob, float2* __restrict__ cs) {
  const int bid = blockIdx.x;
  if (bid < 12288) {
    const float* src;
    ushort_t* dst;
    int i;
    if (bid < 8192) {
      src = x; dst = Xb;
      i = bid * 256 + threadIdx.x;
    } else {
      const int wi = (bid - 8192) >> 10;
      src = (wi == 0) ? wq : (wi == 1) ? wk : (wi == 2) ? wv : wo;
      dst = (wi == 0) ? Wqb : (wi == 1) ? Wkb : (wi == 2) ? Wvb : Wob;
      i = ((bid - 8192) & 1023) * 256 + threadIdx.x;
    }
    f32x4 v = ((const f32x4*)src)[i];
    ushort4 o;
    o.x = f2bf(v.x); o.y = f2bf(v.y); o.z = f2bf(v.z); o.w = f2bf(v.w);
    ((ushort4*)dst)[i] = o;
  } else {
    int idx = (bid - 12288) * 256 + threadIdx.x;  // 4096*32 entries
    int pos = idx >> 5, i = idx & 31;
    double inv = exp2(-(double)i * 0.41524101186092029);  // log2(10000)/32
    double th = (double)pos * inv;
    double s, c;
    sincos(th, &s, &c);
    cs[idx] = make_float2((float)c, (float)s);
  }
}

// ---------------- cross-phase-pipelined NT GEMM ----------------
// BM=128, BN=256, BK=64. 512 thr = 8 waves (2M x 4N), wave tile 64x64.
// C[m][n] = sum_k A[m][k]*W[n][k]; A: MxK bf16 rm, W: NxK bf16 rm.
// LDS 96 KiB: buf b at b*49152: A[128][64] 16K @0, B[256][64] 32K @16384.
// XOR-swizzled chunk layout (slot = chunk ^ (row&7)), pre-swizzled global src.
//
// KEY (fix for R1/R2): phase p issues ds_reads for phase p+1's operands and
// waits them with COUNTED lgkmcnt at p+1 -> LDS reads overlap MFMA.
// Quadrants (8 MFMA each): Q0=m01xn01, Q1=m01xn23, Q2=m23xn01, Q3=m23xn23.
//   Q0: lgkm0[aX,bX ready]; issue bY(B23,cb);            MFMA Q0
//   Q1: issue aY(A23,cb); lgkm(4)[bY done]; BAR;
//       stage B(j+2)->cb.B (all cb.B reads done);        MFMA Q1
//   Q2: lgkm0[aY done]; vmcnt(4)[stage(j+1) done, keep stageB(j+2)]; BAR;
//       stage A(j+2)->cb.A; issue aX'(nb);               MFMA Q2
//   Q3: issue bX'(nb);                                   MFMA Q3
// Counted waits use N <= younger-group size => older group fully retired
// even if the compiler splits b128 reads. 2 barriers/tile; vm never drains
// mid-loop (4 stage-loads always in flight).
template <int OUTBF>
__global__ __launch_bounds__(512, 2) void gemmp(
    const ushort_t* __restrict__ A,
    const ushort_t* __restrict__ W0, const ushort_t* __restrict__ W1, const ushort_t* __restrict__ W2,
    void* __restrict__ C0, void* __restrict__ C1, void* __restrict__ C2,
    int K, int N) {
  __shared__ __align__(16) char smem[98304];
  const int z = blockIdx.z;
  const ushort_t* W = (z == 0) ? W0 : (z == 1 ? W1 : W2);
  void* Cv = (z == 0) ? C0 : (z == 1 ? C1 : C2);

  const int t = threadIdx.x;
  const int lane = t & 63;
  const int l15 = lane & 15, quad = lane >> 4;
  const int wave = t >> 6;
  const int wm = wave >> 2, wn = wave & 3;  // 2M x 4N
  const int bm = blockIdx.x, bn = blockIdx.y;

  // staging: thread t -> row t>>3 (64 rows/call), LDS chunk t&7,
  // global chunk (t&7)^(row&7) (row&7 invariant per 64-row call).
  const int r0 = t >> 3;
  const int gc = (t & 7) ^ (r0 & 7);
  const ushort_t* Ag = A + (size_t)(bm * 128 + r0) * K + gc * 8;
  const ushort_t* Wg = W + (size_t)(bn * 256 + r0) * K + gc * 8;
  const size_t q64K = (size_t)64 * K;
  const int woff = wave * 1024;  // wave-uniform dest slice (+ lane*16 by HW)

  // fragment read offsets (bytes within buffer). slot=(ks*4+quad)^(l15&7);
  // ks=1 -> ^64. frag f adds f*2048 (16 rows x 128B).
  const int sl0 = (quad ^ (l15 & 7)) * 16;
  const int aof = (wm * 64 + l15) * 128 + sl0;
  const int bof = 16384 + (wn * 64 + l15) * 128 + sl0;

  const int KT = K >> 6;  // requires KT >= 3

  const f32x4 zero4 = {0.f, 0.f, 0.f, 0.f};
  f32x4 acc[4][4];
#pragma unroll
  for (int i = 0; i < 4; ++i)
#pragma unroll
    for (int j = 0; j < 4; ++j) acc[i][j] = zero4;

  auto stA = [&](int buf, int q, int kt) {
    gl_lds16(Ag + (size_t)q * q64K + (size_t)kt * 64,
             smem + buf * 49152 + q * 8192 + woff);
  };
  auto stB = [&](int buf, int q, int kt) {
    gl_lds16(Wg + (size_t)q * q64K + (size_t)kt * 64,
             smem + buf * 49152 + 16384 + q * 8192 + woff);
  };

  // prologue: stage tile0 (B 4 + A 2) then tile1 (B 4 + A 2) = 12 vm;
  // retire tile0 (vmcnt(6) keeps tile1's 6 in flight); then issue aX/bX reads.
#pragma unroll
  for (int q = 0; q < 4; ++q) stB(0, q, 0);
  stA(0, 0, 0); stA(0, 1, 0);
#pragma unroll
  for (int q = 0; q < 4; ++q) stB(1, q, 1);
  stA(1, 0, 1); stA(1, 1, 1);
  asm volatile("s_waitcnt vmcnt(6)" ::: "memory");
  __builtin_amdgcn_s_barrier();

  bf16x8 aX[2][2], aY[2][2], bX[2][2], bY[2][2];
  {
    const char* b0 = smem;
#pragma unroll
    for (int m = 0; m < 2; ++m) {
      const int o = aof + m * 2048;
      aX[m][0] = *(const bf16x8*)(b0 + o);
      aX[m][1] = *(const bf16x8*)(b0 + (o ^ 64));
    }
#pragma unroll
    for (int n = 0; n < 2; ++n) {
      const int o = bof + n * 2048;
      bX[n][0] = *(const bf16x8*)(b0 + o);
      bX[n][1] = *(const bf16x8*)(b0 + (o ^ 64));
    }
  }

  for (int j = 0; j < KT; ++j) {
    const int cb = j & 1, nb = cb ^ 1;
    const char* bufc = smem + cb * 49152;
    const char* bufn = smem + nb * 49152;
    const bool st = (j + 2 < KT);
    const bool rd = (j + 1 < KT);
    const int k2 = j + 2;

    // ---- Q0: wait aX/bX; issue bY(B23); MFMA m01 x n01 ----
    asm volatile("s_waitcnt lgkmcnt(0)" ::: "memory");
    __builtin_amdgcn_sched_barrier(0);
#pragma unroll
    for (int n = 0; n < 2; ++n) {
      const int o = bof + (n + 2) * 2048;
      bY[n][0] = *(const bf16x8*)(bufc + o);
      bY[n][1] = *(const bf16x8*)(bufc + (o ^ 64));
    }
    __builtin_amdgcn_sched_barrier(0);
    __builtin_amdgcn_s_setprio(1);
#pragma unroll
    for (int m = 0; m < 2; ++m)
#pragma unroll
      for (int n = 0; n < 2; ++n) {
        acc[m][n] = MFMA16(aX[m][0], bX[n][0], acc[m][n]);
        acc[m][n] = MFMA16(aX[m][1], bX[n][1], acc[m][n]);
      }
    __builtin_amdgcn_s_setprio(0);
    __builtin_amdgcn_sched_barrier(0);

    // ---- Q1: issue aY(A23); wait bY; BAR; stage B(j+2); MFMA m01 x n23 ----
#pragma unroll
    for (int m = 0; m < 2; ++m) {
      const int o = aof + (m + 2) * 2048;
      aY[m][0] = *(const bf16x8*)(bufc + o);
      aY[m][1] = *(const bf16x8*)(bufc + (o ^ 64));
    }
    asm volatile("s_waitcnt lgkmcnt(4)" ::: "memory");
    __builtin_amdgcn_s_barrier();
    if (st) {
#pragma unroll
      for (int q = 0; q < 4; ++q) stB(cb, q, k2);
    }
    __builtin_amdgcn_sched_barrier(0);
    __builtin_amdgcn_s_setprio(1);
#pragma unroll
    for (int m = 0; m < 2; ++m)
#pragma unroll
      for (int n = 0; n < 2; ++n) {
        acc[m][n + 2] = MFMA16(aX[m][0], bY[n][0], acc[m][n + 2]);
        acc[m][n + 2] = MFMA16(aX[m][1], bY[n][1], acc[m][n + 2]);
      }
    __builtin_amdgcn_s_setprio(0);
    __builtin_amdgcn_sched_barrier(0);

    // ---- Q2: wait aY; retire stage(j+1) (keep stageB(j+2)); BAR;
    //          stage A(j+2); issue aX'(nb); MFMA m23 x n01 ----
    asm volatile("s_waitcnt lgkmcnt(0)" ::: "memory");
    if (st) {
      asm volatile("s_waitcnt vmcnt(4)" ::: "memory");
    } else if (rd) {
      asm volatile("s_waitcnt vmcnt(0)" ::: "memory");
    }
    __builtin_amdgcn_s_barrier();
    if (st) { stA(cb, 0, k2); stA(cb, 1, k2); }
    if (rd) {
#pragma unroll
      for (int m = 0; m < 2; ++m) {
        const int o = aof + m * 2048;
        aX[m][0] = *(const bf16x8*)(bufn + o);
        aX[m][1] = *(const bf16x8*)(bufn + (o ^ 64));
      }
    }
    __builtin_amdgcn_sched_barrier(0);
    __builtin_amdgcn_s_setprio(1);
#pragma unroll
    for (int m = 0; m < 2; ++m)
#pragma unroll
      for (int n = 0; n < 2; ++n) {
        acc[m + 2][n] = MFMA16(aY[m][0], bX[n][0], acc[m + 2][n]);
        acc[m + 2][n] = MFMA16(aY[m][1], bX[n][1], acc[m + 2][n]);
      }
    __builtin_amdgcn_s_setprio(0);
    __builtin_amdgcn_sched_barrier(0);

    // ---- Q3: issue bX'(nb); MFMA m23 x n23 ----
    if (rd) {
#pragma unroll
      for (int n = 0; n < 2; ++n) {
        const int o = bof + n * 2048;
        bX[n][0] = *(const bf16x8*)(bufn + o);
        bX[n][1] = *(const bf16x8*)(bufn + (o ^ 64));
      }
    }
    __builtin_amdgcn_sched_barrier(0);
    __builtin_amdgcn_s_setprio(1);
#pragma unroll
    for (int m = 0; m < 2; ++m)
#pragma unroll
      for (int n = 0; n < 2; ++n) {
        acc[m + 2][n + 2] = MFMA16(aY[m][0], bY[n][0], acc[m + 2][n + 2]);
        acc[m + 2][n + 2] = MFMA16(aY[m][1], bY[n][1], acc[m + 2][n + 2]);
      }
    __builtin_amdgcn_s_setprio(0);
    __builtin_amdgcn_sched_barrier(0);
  }

  // ---- epilogue: C/D mapping col=l15, row=quad*4+r (verified) ----
  const int rbase = bm * 128 + wm * 64 + quad * 4;
  const int cbase = bn * 256 + wn * 64 + l15;
#pragma unroll
  for (int m = 0; m < 4; ++m)
#pragma unroll
    for (int n = 0; n < 4; ++n)
#pragma unroll
      for (int r = 0; r < 4; ++r) {
        size_t idx = (size_t)(rbase + m * 16 + r) * N + (cbase + n * 16);
        if (OUTBF)
          ((ushort_t*)Cv)[idx] = f2bf(acc[m][n][r]);
        else
          ((float*)Cv)[idx] = acc[m][n][r];
      }
}

// ---------------- fused windowed attention (unchanged) ----------------
static __device__ __forceinline__ void rope8(const ushort_t* __restrict__ g,
                                             ushort_t* __restrict__ lds,
                                             const float2* __restrict__ cs4, float scale) {
  uint4 raw = *(const uint4*)g;
  unsigned rw[4] = {raw.x, raw.y, raw.z, raw.w};
  ushort_t o[8];
#pragma unroll
  for (int m = 0; m < 4; ++m) {
    float x1 = bf2f((ushort_t)(rw[m] & 0xffffu));
    float x2 = bf2f((ushort_t)(rw[m] >> 16));
    float2 sc = cs4[m];
    o[2 * m]     = f2bf((x1 * sc.x - x2 * sc.y) * scale);
    o[2 * m + 1] = f2bf((x1 * sc.y + x2 * sc.x) * scale);
  }
  uint4 w;
  w.x = (unsigned)o[0] | ((unsigned)o[1] << 16);
  w.y = (unsigned)o[2] | ((unsigned)o[3] << 16);
  w.z = (unsigned)o[4] | ((unsigned)o[5] << 16);
  w.w = (unsigned)o[6] | ((unsigned)o[7] << 16);
  *(uint4*)lds = w;  // ds_write_b128
}

__global__ __launch_bounds__(256, 2) void attn(
    const ushort_t* __restrict__ Qb, const ushort_t* __restrict__ Kb,
    const ushort_t* __restrict__ Vb, ushort_t* __restrict__ Yb,
    const float2* __restrict__ cs) {
  __shared__ __align__(16) ushort_t smem[27648];
  ushort_t* Qs = smem;
  ushort_t* Ks = smem + 9216;
  ushort_t* Vt = smem;
  ushort_t* Pc = smem + 16896;

  const int t = threadIdx.x;
  const int lane = t & 63, wave = t >> 6;
  const int l15 = lane & 15, quad = lane >> 4;
  const int win = blockIdx.x >> 1, slice = blockIdx.x & 1;
  const int h = blockIdx.y, b = blockIdx.z;
  const int kBase = win * 256, qBase = kBase + slice * 128;
  const size_t gbase = ((size_t)b * 4096) * 1024 + h * 64;

  const int sr = t >> 3;
  const int c0 = (t & 7) * 8;

#pragma unroll
  for (int p = 0; p < 4; ++p) {
    int r = p * 32 + sr;
    rope8(Qb + gbase + (size_t)(qBase + r) * 1024 + c0, Qs + r * 72 + c0,
          cs + (qBase + r) * 32 + (c0 >> 1), 0.125f);
  }
#pragma unroll
  for (int p = 0; p < 8; ++p) {
    int r = p * 32 + sr;
    rope8(Kb + gbase + (size_t)(kBase + r) * 1024 + c0, Ks + r * 72 + c0,
          cs + (kBase + r) * 32 + (c0 >> 1), 1.0f);
  }
  __syncthreads();

  const int qw = wave * 32;
  const f32x4 zero4 = {0.f, 0.f, 0.f, 0.f};
  f32x4 S[2][16];
#pragma unroll
  for (int i = 0; i < 2; ++i)
#pragma unroll
    for (int j = 0; j < 16; ++j) S[i][j] = zero4;
#pragma unroll
  for (int ks = 0; ks < 2; ++ks) {
    bf16x8 a0 = *(const bf16x8*)&Qs[(qw + l15) * 72 + ks * 32 + quad * 8];
    bf16x8 a1 = *(const bf16x8*)&Qs[(qw + 16 + l15) * 72 + ks * 32 + quad * 8];
#pragma unroll
    for (int j = 0; j < 16; ++j) {
      bf16x8 bk = *(const bf16x8*)&Ks[(j * 16 + l15) * 72 + ks * 32 + quad * 8];
      S[0][j] = MFMA16(a0, bk, S[0][j]);
      S[1][j] = MFMA16(a1, bk, S[1][j]);
    }
  }

  float linv[2][4];
#pragma unroll
  for (int i = 0; i < 2; ++i)
#pragma unroll
    for (int r = 0; r < 4; ++r) {
      float mx = S[i][0][r];
#pragma unroll
      for (int j = 1; j < 16; ++j) mx = fmaxf(mx, S[i][j][r]);
      mx = fmaxf(mx, __shfl_xor(mx, 1));
      mx = fmaxf(mx, __shfl_xor(mx, 2));
      mx = fmaxf(mx, __shfl_xor(mx, 4));
      mx = fmaxf(mx, __shfl_xor(mx, 8));
      float sum = 0.f;
#pragma unroll
      for (int j = 0; j < 16; ++j) {
        float e = __expf(S[i][j][r] - mx);
        S[i][j][r] = e;
        sum += e;
      }
      sum += __shfl_xor(sum, 1);
      sum += __shfl_xor(sum, 2);
      sum += __shfl_xor(sum, 4);
      sum += __shfl_xor(sum, 8);
      linv[i][r] = 1.0f / sum;
    }
  __syncthreads();

#pragma unroll
  for (int p = 0; p < 8; ++p) {
    int k = p * 32 + sr;
    uint4 raw = *(const uint4*)(Vb + gbase + (size_t)(kBase + k) * 1024 + c0);
    ushort_t vv[8];
    vv[0] = raw.x & 0xffffu; vv[1] = raw.x >> 16;
    vv[2] = raw.y & 0xffffu; vv[3] = raw.y >> 16;
    vv[4] = raw.z & 0xffffu; vv[5] = raw.z >> 16;
    vv[6] = raw.w & 0xffffu; vv[7] = raw.w >> 16;
#pragma unroll
    for (int e = 0; e < 8; ++e) {
      int ee = (e + (t & 7)) & 7;
      Vt[(c0 + ee) * 264 + k] = vv[ee];
    }
  }

  auto writeP = [&](int kc) {
#pragma unroll
    for (int i = 0; i < 2; ++i)
#pragma unroll
      for (int jj = 0; jj < 4; ++jj) {
        int j = kc * 4 + jj;
#pragma unroll
        for (int r = 0; r < 4; ++r)
          Pc[(qw + i * 16 + quad * 4 + r) * 72 + jj * 16 + l15] = f2bf(S[i][j][r]);
      }
  };

  writeP(0);
  __syncthreads();

  f32x4 O[2][4];
#pragma unroll
  for (int i = 0; i < 2; ++i)
#pragma unroll
    for (int jd = 0; jd < 4; ++jd) O[i][jd] = zero4;

  for (int kc = 0; kc < 4; ++kc) {
#pragma unroll
    for (int ks = 0; ks < 2; ++ks) {
      bf16x8 a0 = *(const bf16x8*)&Pc[(qw + l15) * 72 + ks * 32 + quad * 8];
      bf16x8 a1 = *(const bf16x8*)&Pc[(qw + 16 + l15) * 72 + ks * 32 + quad * 8];
#pragma unroll
      for (int jd = 0; jd < 4; ++jd) {
        bf16x8 bv = *(const bf16x8*)&Vt[(jd * 16 + l15) * 264 + kc * 64 + ks * 32 + quad * 8];
        O[0][jd] = MFMA16(a0, bv, O[0][jd]);
        O[1][jd] = MFMA16(a1, bv, O[1][jd]);
      }
    }
    if (kc < 3) {
      __syncthreads();
      writeP(kc + 1);
      __syncthreads();
    }
  }

#pragma unroll
  for (int i = 0; i < 2; ++i)
#pragma unroll
    for (int jd = 0; jd < 4; ++jd)
#pragma unroll
      for (int r = 0; r < 4; ++r) {
        int row = qBase + qw + i * 16 + quad * 4 + r;
        int col = jd * 16 + l15;
        Yb[gbase + (size_t)row * 1024 + col] = f2bf(O[i][jd][r] * linv[i][r]);
      }
}

// ---------------- launch ----------------
extern "C" void kernel_launch(void* const* d_in, const int* in_sizes, int n_in,
                              void* d_out, int out_size, void* d_ws, size_t ws_size,
                              hipStream_t stream) {
  (void)in_sizes; (void)n_in; (void)out_size; (void)ws_size;
  const float* x  = (const float*)d_in[0];
  const float* wq = (const float*)d_in[1];
  const float* wk = (const float*)d_in[2];
  const float* wv = (const float*)d_in[3];
  const float* wo = (const float*)d_in[4];

  char* ws = (char*)d_ws;
  // workspace layout (bytes): Xb 16M | Wq..Wo 4x2M | Qb 16M | Kb 16M | Vb 16M | Yb 16M | cs 1M
  ushort_t* Xb  = (ushort_t*)(ws);
  ushort_t* Wqb = (ushort_t*)(ws + 16777216);
  ushort_t* Wkb = Wqb + 1048576;
  ushort_t* Wvb = Wkb + 1048576;
  ushort_t* Wob = Wvb + 1048576;
  ushort_t* Qb  = (ushort_t*)(ws + 25165824);
  ushort_t* Kb  = Qb + 8388608;
  ushort_t* Vb  = Kb + 8388608;
  ushort_t* Yb  = Vb + 8388608;
  float2*   cs  = (float2*)(ws + 92274688);

  prep<<<dim3(12800), dim3(256), 0, stream>>>(x, wq, wk, wv, wo,
                                              Xb, Wqb, Wkb, Wvb, Wob, cs);

  // QKV: M=8192 -> 64 x-tiles, N=1024 -> 4 y-tiles, 3 weights: 768 blocks
  //      = 3 perfect rounds @ 1 block/CU.
  gemmp<1><<<dim3(64, 4, 3), dim3(512), 0, stream>>>(
      Xb, Wqb, Wkb, Wvb, (void*)Qb, (void*)Kb, (void*)Vb, 1024, 1024);

  attn<<<dim3(32, 16, 2), dim3(256), 0, stream>>>(Qb, Kb, Vb, Yb, cs);

  // proj: 256 blocks = 1 perfect round
  gemmp<0><<<dim3(64, 4, 1), dim3(512), 0, stream>>>(
      Yb, Wob, Wob, Wob, d_out, d_out, d_out, 1024, 1024);
}